// Round 2
// baseline (583.681 us; speedup 1.0000x reference)
//
#include <hip/hip_runtime.h>
#include <hip/hip_bf16.h>
#include <cstdint>
#include <cstddef>

#define H 256
#define CHUNK 128     // max items per pooling chunk

typedef __attribute__((ext_vector_type(8))) short    frag8;   // 8 bf16 (4 VGPRs)
typedef __attribute__((ext_vector_type(4))) float    f32x4;
typedef __attribute__((ext_vector_type(4))) uint32_t u32x4;
typedef __attribute__((ext_vector_type(8))) unsigned short ushort8;

__device__ __forceinline__ unsigned short f32_to_bf16(float f) {
    uint32_t u = __float_as_uint(f);
    u = (u + 0x7FFFu + ((u >> 16) & 1u)) >> 16;   // RNE
    return (unsigned short)u;
}

// packed f32x2 -> bf16x2 (v_cvt_pk_bf16_f32 on gfx950), a in low 16 bits
__device__ __forceinline__ uint32_t pk_bf16(float a, float b) {
    union { __hip_bfloat162 h2; uint32_t u; } cv;
    cv.h2 = __float22bfloat162_rn(make_float2(a, b));
    return cv.u;
}

// ---------------- kernel 1: prep — Wopt fragment-shuffle + Wout transpose ----------------
__global__ void prep(const float* __restrict__ Wu, const float* __restrict__ Wv,
                     const float* __restrict__ Wout,
                     unsigned short* __restrict__ Wopt, float* __restrict__ WoutT) {
    int bid = blockIdx.x, tid = threadIdx.x;
    if (bid < 64) {
        int idx  = bid * 256 + tid;        // 0..16383
        int lane = idx & 63;
        int ct   = (idx >> 6) & 15;
        int ksg  = idx >> 10;
        int col  = ct * 16 + (lane & 15);
        int kg   = ksg * 32 + (lane >> 4) * 8;
        ushort8 pk;
        #pragma unroll
        for (int j = 0; j < 8; j++) {
            int k = kg + j;
            float v = (k < 256) ? Wu[col * 256 + k] : Wv[col * 256 + (k - 256)];
            pk[j] = f32_to_bf16(v);
        }
        *(ushort8*)&Wopt[(size_t)idx * 8] = pk;
    } else {
        int t2 = (bid - 64) * 256 + tid;   // 0..65535
        int j = t2 & 255, k = t2 >> 8;
        WoutT[t2] = Wout[j * 256 + k];     // WoutT[k][j] = Wout[j][k]
    }
}

// ---------------- kernel 2: dual exclusive scan: item offsets + chunk work-list ----------------
__global__ void seg_offsets(const int* __restrict__ lens, int B, int* __restrict__ off,
                            int2* __restrict__ chunks, int* __restrict__ chunk_cnt) {
    __shared__ int partL[256], partC[256];
    int tid = threadIdx.x;
    bool is64 = (B >= 3) && (lens[1] == 0) && (lens[3] == 0) && (lens[5] == 0);
    int per = (B + 255) / 256;
    int base = tid * per;
    int sL = 0, sC = 0;
    for (int i = 0; i < per; i++) {
        int idx = base + i;
        if (idx < B) {
            int l = is64 ? lens[2 * idx] : lens[idx];
            sL += l;
            sC += (l + CHUNK - 1) / CHUNK;
        }
    }
    partL[tid] = sL; partC[tid] = sC;
    __syncthreads();
    for (int d = 1; d < 256; d <<= 1) {
        int vL = partL[tid], vC = partC[tid];
        int aL = (tid >= d) ? partL[tid - d] : 0;
        int aC = (tid >= d) ? partC[tid - d] : 0;
        __syncthreads();
        partL[tid] = vL + aL; partC[tid] = vC + aC;
        __syncthreads();
    }
    int runL = partL[tid] - sL;
    int runC = partC[tid] - sC;
    for (int i = 0; i < per; i++) {
        int idx = base + i;
        if (idx < B) {
            int l = is64 ? lens[2 * idx] : lens[idx];
            off[idx] = runL;
            int n = (l + CHUNK - 1) / CHUNK;
            for (int c = 0; c < n; c++)
                chunks[runC + c] = make_int2(idx, runL + c * CHUNK);
            runC += n;
            runL += l;
        }
    }
    if (tid == 255) { off[B] = partL[255]; chunk_cnt[0] = partC[255]; }
}

// ---------------- kernel 3: fused e = We . sigmoid(Wu f + bu + Wv c) ----------------
// Persistent-ish: 512 blocks (2/CU), each grid-strides over ~6-7 row-tiles of 64.
// Per K-step (kt): ONE barrier, LDS double-buffer. Step t: {B-frag loads; ks-loop
// MFMA on buf[cur]; convert+write A(t+1) -> buf[cur^1]; issue A(t+2) loads; barrier}.
// A loads always one full step ahead (~HBM latency); in-order vmcnt means the
// B-frag waits retire A(t+1) before the convert needs it -> stall-free convert.
// Cross-tile: at kt=2/3 the next tile's kt=0/1 strips are already being fetched.
__global__ __launch_bounds__(512, 4) void fused_e(
        const float* __restrict__ feats, const float* __restrict__ ctx,
        const unsigned short* __restrict__ Wopt,
        const float* __restrict__ bu, const float* __restrict__ We,
        float* __restrict__ e_out, int nTiles) {
    __shared__ unsigned short a_lds[2][64 * 128];   // 32 KB double-buffer
    __shared__ float e_part[8 * 64];                // 2 KB

    const int tid  = threadIdx.x;
    const int lane = tid & 63;
    const int w    = tid >> 6;          // wave 0..7 -> cols w*32..w*32+31
    const int l15  = lane & 15;
    const int q    = lane >> 4;
    const int r0   = tid >> 3;          // staging row 0..63
    const int c8   = tid & 7;           // 16-float chunk within 128 cols
    const int swz  = r0 & 15;
    const int G    = gridDim.x;

    if (blockIdx.x >= nTiles) return;   // block-uniform

    float buv[2], wev[2];
    #pragma unroll
    for (int ci = 0; ci < 2; ++ci) {
        int col = w * 32 + ci * 16 + l15;
        buv[ci] = bu[col];
        wev[ci] = We[col];
    }

    f32x4 acc[4][2];
    #pragma unroll
    for (int i = 0; i < 4; i++)
        #pragma unroll
        for (int j = 0; j < 2; j++)
            acc[i][j] = (f32x4)(0.0f);

    f32x4 pre[4];
    auto loadA = [&](int tile, int kt) {
        const float* s = (kt < 2) ? feats : ctx;
        const float* p = s + ((size_t)tile * 64 + r0) * H + ((kt & 1) << 7) + (c8 << 4);
        pre[0] = *(const f32x4*)p;       pre[1] = *(const f32x4*)(p + 4);
        pre[2] = *(const f32x4*)(p + 8); pre[3] = *(const f32x4*)(p + 12);
    };
    auto cvt_store = [&](int buf) {
        u32x4 g0, g1;
        g0[0] = pk_bf16(pre[0][0], pre[0][1]); g0[1] = pk_bf16(pre[0][2], pre[0][3]);
        g0[2] = pk_bf16(pre[1][0], pre[1][1]); g0[3] = pk_bf16(pre[1][2], pre[1][3]);
        g1[0] = pk_bf16(pre[2][0], pre[2][1]); g1[1] = pk_bf16(pre[2][2], pre[2][3]);
        g1[2] = pk_bf16(pre[3][0], pre[3][1]); g1[3] = pk_bf16(pre[3][2], pre[3][3]);
        *(u32x4*)&a_lds[buf][r0 * 128 + (((2 * c8    ) ^ swz) * 8)] = g0;
        *(u32x4*)&a_lds[buf][r0 * 128 + (((2 * c8 + 1) ^ swz) * 8)] = g1;
    };

    // prologue: stage (tile0,0) into buf0; issue (tile0,1)
    loadA(blockIdx.x, 0);
    cvt_store(0);
    loadA(blockIdx.x, 1);
    __syncthreads();

    int cur = 0;
    for (int tile = blockIdx.x; tile < nTiles; tile += G) {
        #pragma unroll
        for (int kt = 0; kt < 4; ++kt) {
            // B fragments for this step (L2-hot, reused across all tiles)
            frag8 bfr[4][2];
            #pragma unroll
            for (int ks = 0; ks < 4; ++ks)
                #pragma unroll
                for (int ci = 0; ci < 2; ++ci)
                    bfr[ks][ci] = *(const frag8*)&Wopt[
                        (((size_t)(kt * 4 + ks) * 16 + (w * 2 + ci)) * 64 + lane) * 8];

            #pragma unroll
            for (int ks = 0; ks < 4; ++ks) {
                frag8 afr[4];
                #pragma unroll
                for (int rt = 0; rt < 4; ++rt)
                    afr[rt] = *(const frag8*)&a_lds[cur][(rt * 16 + l15) * 128 + (((ks * 4 + q) ^ l15) * 8)];
                #pragma unroll
                for (int rt = 0; rt < 4; ++rt)
                    #pragma unroll
                    for (int ci = 0; ci < 2; ++ci)
                        acc[rt][ci] = __builtin_amdgcn_mfma_f32_16x16x32_bf16(
                            afr[rt], bfr[ks][ci], acc[rt][ci], 0, 0, 0);
            }

            const bool last_step = (kt == 3) && (tile + G >= nTiles);
            if (!last_step) {
                cvt_store(cur ^ 1);               // A(step+1): landed (drained by B waits)
                int kt2 = kt + 2, tile2 = tile;
                if (kt2 >= 4) { kt2 -= 4; tile2 += G; }
                if (tile2 < nTiles) loadA(tile2, kt2);   // A(step+2): in flight across barrier
            }
            cur ^= 1;
            __syncthreads();                      // one barrier per step
        }

        // epilogue: e_row = sum_col We[col] * sigmoid(h + bu[col]); wave covers 32 cols
        #pragma unroll
        for (int rt = 0; rt < 4; ++rt) {
            #pragma unroll
            for (int r = 0; r < 4; ++r) {
                float s = 0.0f;
                #pragma unroll
                for (int ci = 0; ci < 2; ++ci) {
                    float h = acc[rt][ci][r] + buv[ci];
                    s += wev[ci] * __builtin_amdgcn_rcpf(1.0f + __expf(-h));
                    acc[rt][ci][r] = 0.0f;        // reset for next tile
                }
                s += __shfl_xor(s, 1, 64);
                s += __shfl_xor(s, 2, 64);
                s += __shfl_xor(s, 4, 64);
                s += __shfl_xor(s, 8, 64);
                if (l15 == 0) e_part[w * 64 + rt * 16 + q * 4 + r] = s;
            }
        }
        __syncthreads();
        if (tid < 64) {
            float s = 0.0f;
            #pragma unroll
            for (int ww = 0; ww < 8; ++ww) s += e_part[ww * 64 + tid];
            e_out[(size_t)tile * 64 + tid] = s;
        }
        __syncthreads();                          // e_part reuse fence for next tile
    }
}

// ---------------- kernel 4: per-segment softmax stats — MULTI-CHUNK segments only ----------------
// Single-chunk segments (len <= CHUNK, the common case here) are handled locally
// inside pool_chunks; this kernel early-exits for them.
__global__ __launch_bounds__(256) void seg_stats(
        float* __restrict__ e, const int* __restrict__ off, int B) {
    int seg = blockIdx.x * 4 + (threadIdx.x >> 6);
    int lane = threadIdx.x & 63;
    if (seg >= B) return;
    int start = off[seg];
    int len = off[seg + 1] - start;
    if (len <= CHUNK) return;          // handled in pool_chunks
    float m = -3.0e38f;
    for (int i = lane; i < len; i += 64) m = fmaxf(m, e[start + i]);
    #pragma unroll
    for (int o = 32; o > 0; o >>= 1) m = fmaxf(m, __shfl_xor(m, o, 64));
    float s = 0.0f;
    for (int i = lane; i < len; i += 64) s += __expf(e[start + i] - m);
    #pragma unroll
    for (int o = 32; o > 0; o >>= 1) s += __shfl_xor(s, o, 64);
    float inv = (s > 0.0f) ? 1.0f / s : 0.0f;
    for (int i = lane; i < len; i += 64) e[start + i] = __expf(e[start + i] - m) * inv;
}

// ---------------- kernel 5: chunked weighted pooling with fused local softmax ----------------
// Single-chunk segments: compute m/denom in-block from raw e, alpha on the fly.
// Multi-chunk segments: alpha was precomputed in place by seg_stats.
__global__ __launch_bounds__(256) void pool_chunks(
        const float* __restrict__ ealpha, const float* __restrict__ feats,
        const int* __restrict__ off, const int2* __restrict__ chunks,
        const int* __restrict__ chunk_cnt, float* __restrict__ rst) {
    __shared__ float redf[4 * 256];
    __shared__ float smred[8];
    int idx = blockIdx.x;
    if (idx >= chunk_cnt[0]) return;
    int2 en = chunks[idx];
    int seg = en.x, cstart = en.y;
    int sstart = off[seg], send = off[seg + 1];
    int clen = send - cstart;
    if (clen > CHUNK) clen = CHUNK;
    int tid = threadIdx.x, lane = tid & 63, g = tid >> 6;
    const bool multi = (send - sstart) > CHUNK;   // block-uniform

    float m = 0.0f, inv = 1.0f;
    if (!multi) {
        float v = (tid < clen) ? ealpha[cstart + tid] : -3.0e38f;
        #pragma unroll
        for (int o = 32; o > 0; o >>= 1) v = fmaxf(v, __shfl_xor(v, o, 64));
        if (lane == 0) smred[g] = v;
        __syncthreads();
        m = fmaxf(fmaxf(smred[0], smred[1]), fmaxf(smred[2], smred[3]));
        float x = (tid < clen) ? __expf(ealpha[cstart + tid] - m) : 0.0f;
        #pragma unroll
        for (int o = 32; o > 0; o >>= 1) x += __shfl_xor(x, o, 64);
        if (lane == 0) smred[4 + g] = x;
        __syncthreads();
        float ssum = smred[4] + smred[5] + smred[6] + smred[7];
        inv = (ssum > 0.0f) ? 1.0f / ssum : 0.0f;
    }

    const f32x4* F = (const f32x4*)feats + (size_t)cstart * 64 + lane;
    const float* A = ealpha + cstart;
    f32x4 acc0 = (f32x4)(0.0f), acc1 = (f32x4)(0.0f);
    int i = g;
    for (; i + 4 < clen; i += 8) {
        float w0 = A[i], w1 = A[i + 4];
        if (!multi) { w0 = __expf(w0 - m) * inv; w1 = __expf(w1 - m) * inv; }
        acc0 += w0 * F[(size_t)i * 64];
        acc1 += w1 * F[(size_t)(i + 4) * 64];
    }
    if (i < clen) {
        float w0 = A[i];
        if (!multi) w0 = __expf(w0 - m) * inv;
        acc0 += w0 * F[(size_t)i * 64];
    }
    acc0 += acc1;
    *(f32x4*)&redf[g * 256 + lane * 4] = acc0;
    __syncthreads();
    float v = redf[tid] + redf[256 + tid] + redf[512 + tid] + redf[768 + tid];
    if (multi) atomicAdd(&rst[(size_t)seg * H + tid], v);
    else rst[(size_t)seg * H + tid] = v;
}

// ---------------- kernel 6: out = rst @ Wout.T (via WoutT) ----------------
#define RB 8
__global__ __launch_bounds__(256) void out_gemm(
        const float* __restrict__ rst, const float* __restrict__ WoutT,
        float* __restrict__ out) {
    __shared__ float r[RB * 256];
    const int tid = threadIdx.x;
    const size_t b0 = (size_t)blockIdx.x * RB;
    for (int i = tid; i < RB * 256; i += 256) r[i] = rst[b0 * 256 + i];
    __syncthreads();
    float acc[RB];
    #pragma unroll
    for (int j = 0; j < RB; j++) acc[j] = 0.0f;
    for (int k = 0; k < 256; k += 4) {
        f32x4 rw[RB];
        #pragma unroll
        for (int j = 0; j < RB; j++) rw[j] = *(const f32x4*)&r[j * 256 + k];
        #pragma unroll
        for (int kk = 0; kk < 4; kk++) {
            float wv = WoutT[(size_t)(k + kk) * 256 + tid];
            #pragma unroll
            for (int j = 0; j < RB; j++) acc[j] += rw[j][kk] * wv;
        }
    }
    #pragma unroll
    for (int j = 0; j < RB; j++) out[(b0 + j) * 256 + tid] = acc[j];
}

// ---------------- launch ----------------
extern "C" void kernel_launch(void* const* d_in, const int* in_sizes, int n_in,
                              void* d_out, int out_size, void* d_ws, size_t ws_size,
                              hipStream_t stream) {
    const float* feats = (const float*)d_in[0];
    const float* ctx   = (const float*)d_in[1];
    const int*   lens  = (const int*)d_in[2];
    const float* Wu    = (const float*)d_in[3];
    const float* bu    = (const float*)d_in[4];
    const float* Wv    = (const float*)d_in[5];
    const float* We    = (const float*)d_in[6];
    const float* Wout  = (const float*)d_in[7];
    float* out = (float*)d_out;

    const int N = in_sizes[0] / H;    // 204800
    const int B = in_sizes[2];        // 4096
    const int maxChunks = B + (N + CHUNK - 1) / CHUNK;
    const int nTiles = N / 64;        // 3200

    char* w = (char*)d_ws;
    auto carve = [&](size_t bytes) {
        char* p = w;
        w += (bytes + 255) & ~(size_t)255;
        return p;
    };
    int*            off    = (int*)           carve((size_t)(B + 1) * sizeof(int));
    float*          e      = (float*)         carve((size_t)N * sizeof(float));
    float*          rst    = (float*)         carve((size_t)B * H * sizeof(float));
    unsigned short* Wopt   = (unsigned short*)carve((size_t)16 * 16 * 64 * 8 * sizeof(unsigned short));
    float*          WoutT  = (float*)         carve((size_t)H * H * sizeof(float));
    int2*           chunks = (int2*)          carve((size_t)maxChunks * sizeof(int2));
    int*            ccnt   = (int*)           carve(sizeof(int));

    hipMemsetAsync(rst, 0, (size_t)B * H * sizeof(float), stream);  // for atomic combine

    const int gE = (nTiles < 512) ? nTiles : 512;   // 2 blocks/CU, persistent-ish

    prep        <<<320,         256, 0, stream>>>(Wu, Wv, Wout, Wopt, WoutT);
    seg_offsets <<<1,           256, 0, stream>>>(lens, B, off, chunks, ccnt);
    fused_e     <<<gE,          512, 0, stream>>>(feats, ctx, Wopt, bu, We, e, nTiles);
    seg_stats   <<<(B + 3) / 4, 256, 0, stream>>>(e, off, B);
    pool_chunks <<<maxChunks,   256, 0, stream>>>(e, feats, off, chunks, ccnt, rst);
    out_gemm    <<<B / RB,      256, 0, stream>>>(rst, WoutT, out);
}

// Round 3
// 547.056 us; speedup vs baseline: 1.0669x; 1.0669x over previous
//
#include <hip/hip_runtime.h>
#include <hip/hip_bf16.h>
#include <cstdint>
#include <cstddef>

#define H 256
#define CHUNK 128     // max items per pooling chunk

typedef __attribute__((ext_vector_type(8))) short    frag8;   // 8 bf16 (4 VGPRs)
typedef __attribute__((ext_vector_type(4))) float    f32x4;
typedef __attribute__((ext_vector_type(4))) uint32_t u32x4;
typedef __attribute__((ext_vector_type(8))) unsigned short ushort8;

__device__ __forceinline__ unsigned short f32_to_bf16(float f) {
    uint32_t u = __float_as_uint(f);
    u = (u + 0x7FFFu + ((u >> 16) & 1u)) >> 16;   // RNE
    return (unsigned short)u;
}

// packed f32x2 -> bf16x2 (v_cvt_pk_bf16_f32 on gfx950), a in low 16 bits
__device__ __forceinline__ uint32_t pk_bf16(float a, float b) {
    union { __hip_bfloat162 h2; uint32_t u; } cv;
    cv.h2 = __float22bfloat162_rn(make_float2(a, b));
    return cv.u;
}

// ---------------- kernel 1: prep (Wopt shuffle + WoutT) + seg_offsets scan, merged ----------------
// blocks 0..63: Wopt fragment-shuffle; 64..319: Wout transpose; 320: dual scan.
__global__ void prep_scan(const float* __restrict__ Wu, const float* __restrict__ Wv,
                          const float* __restrict__ Wout,
                          unsigned short* __restrict__ Wopt, float* __restrict__ WoutT,
                          const int* __restrict__ lens, int B, int* __restrict__ off,
                          int2* __restrict__ chunks, int* __restrict__ chunk_cnt) {
    __shared__ int partL[256], partC[256];
    int bid = blockIdx.x, tid = threadIdx.x;
    if (bid < 64) {
        int idx  = bid * 256 + tid;        // 0..16383
        int lane = idx & 63;
        int ct   = (idx >> 6) & 15;
        int ksg  = idx >> 10;
        int col  = ct * 16 + (lane & 15);
        int kg   = ksg * 32 + (lane >> 4) * 8;
        ushort8 pk;
        #pragma unroll
        for (int j = 0; j < 8; j++) {
            int k = kg + j;
            float v = (k < 256) ? Wu[col * 256 + k] : Wv[col * 256 + (k - 256)];
            pk[j] = f32_to_bf16(v);
        }
        *(ushort8*)&Wopt[(size_t)idx * 8] = pk;
    } else if (bid < 320) {
        int t2 = (bid - 64) * 256 + tid;   // 0..65535
        int j = t2 & 255, k = t2 >> 8;
        WoutT[t2] = Wout[j * 256 + k];     // WoutT[k][j] = Wout[j][k]
    } else {
        // dual exclusive scan: item offsets + chunk work-list (single block)
        bool is64 = (B >= 3) && (lens[1] == 0) && (lens[3] == 0) && (lens[5] == 0);
        int per = (B + 255) / 256;
        int base = tid * per;
        int sL = 0, sC = 0;
        for (int i = 0; i < per; i++) {
            int idx = base + i;
            if (idx < B) {
                int l = is64 ? lens[2 * idx] : lens[idx];
                sL += l;
                sC += (l + CHUNK - 1) / CHUNK;
            }
        }
        partL[tid] = sL; partC[tid] = sC;
        __syncthreads();
        for (int d = 1; d < 256; d <<= 1) {
            int vL = partL[tid], vC = partC[tid];
            int aL = (tid >= d) ? partL[tid - d] : 0;
            int aC = (tid >= d) ? partC[tid - d] : 0;
            __syncthreads();
            partL[tid] = vL + aL; partC[tid] = vC + aC;
            __syncthreads();
        }
        int runL = partL[tid] - sL;
        int runC = partC[tid] - sC;
        for (int i = 0; i < per; i++) {
            int idx = base + i;
            if (idx < B) {
                int l = is64 ? lens[2 * idx] : lens[idx];
                off[idx] = runL;
                int n = (l + CHUNK - 1) / CHUNK;
                for (int c = 0; c < n; c++)
                    chunks[runC + c] = make_int2(idx, runL + c * CHUNK);
                runC += n;
                runL += l;
            }
        }
        if (tid == 255) { off[B] = partL[255]; chunk_cnt[0] = partC[255]; }
    }
}

// ---------------- kernel 2: fused e = We . sigmoid(Wu f + bu + Wv c) ----------------
// 512 thr (8 waves), 64 rows x 256 cols, K=512 in 4 steps of KT=128.
// LDS double-buffer (2x16KB), ONE barrier per step, A-load lead = 2 steps
// (HBM ~900cy fully covered by ~2 step bodies). Straight-line unrolled,
// no lambdas/persistence (round-2's spill source). acc[4][2]=32 AGPR,
// pre 2x16 VGPR; target <=128 regs -> 2 blocks/CU.
// LDS layout: 64x128 bf16, XOR-swizzle in 16B groups (group' = group ^ (row&15)).
__global__ __launch_bounds__(512, 4) void fused_e(
        const float* __restrict__ feats, const float* __restrict__ ctx,
        const unsigned short* __restrict__ Wopt,
        const float* __restrict__ bu, const float* __restrict__ We,
        float* __restrict__ e_out) {
    __shared__ unsigned short a_lds[2][64 * 128];   // 32 KB
    __shared__ float e_part[8 * 64];                // 2 KB

    const int tid  = threadIdx.x;
    const int lane = tid & 63;
    const int w    = tid >> 6;          // wave 0..7 -> cols w*32..w*32+31
    const int l15  = lane & 15;
    const int q    = lane >> 4;
    const size_t m0 = (size_t)blockIdx.x * 64;
    const int r0   = tid >> 3;          // staging row 0..63
    const int c8   = tid & 7;           // 16-float chunk within 128 cols
    const int swz  = r0 & 15;

    float buv[2], wev[2];
    #pragma unroll
    for (int ci = 0; ci < 2; ++ci) {
        int col = w * 32 + ci * 16 + l15;
        buv[ci] = bu[col];
        wev[ci] = We[col];
    }

    f32x4 acc[4][2];
    #pragma unroll
    for (int i = 0; i < 4; i++)
        #pragma unroll
        for (int j = 0; j < 2; j++)
            acc[i][j] = (f32x4)(0.0f);

    f32x4 pa0, pa1, pa2, pa3, pb0, pb1, pb2, pb3;

#define LOADA(d0, d1, d2, d3, kt_) do {                                          \
    const float* _s = ((kt_) < 2) ? feats : ctx;                                 \
    const float* _p = _s + (m0 + r0) * H + (((kt_) & 1) << 7) + (c8 << 4);       \
    d0 = *(const f32x4*)_p;       d1 = *(const f32x4*)(_p + 4);                  \
    d2 = *(const f32x4*)(_p + 8); d3 = *(const f32x4*)(_p + 12); } while (0)

#define CVTST(buf_, s0, s1, s2, s3) do {                                         \
    u32x4 g0, g1;                                                                \
    g0[0] = pk_bf16(s0[0], s0[1]); g0[1] = pk_bf16(s0[2], s0[3]);                \
    g0[2] = pk_bf16(s1[0], s1[1]); g0[3] = pk_bf16(s1[2], s1[3]);                \
    g1[0] = pk_bf16(s2[0], s2[1]); g1[1] = pk_bf16(s2[2], s2[3]);                \
    g1[2] = pk_bf16(s3[0], s3[1]); g1[3] = pk_bf16(s3[2], s3[3]);                \
    *(u32x4*)&a_lds[buf_][r0 * 128 + (((2 * c8    ) ^ swz) * 8)] = g0;           \
    *(u32x4*)&a_lds[buf_][r0 * 128 + (((2 * c8 + 1) ^ swz) * 8)] = g1; } while (0)

#define STEP(kt_, buf_) do {                                                     \
    _Pragma("unroll")                                                            \
    for (int ks = 0; ks < 4; ++ks) {                                             \
        frag8 bfr[2];                                                            \
        _Pragma("unroll")                                                        \
        for (int ci = 0; ci < 2; ++ci)                                           \
            bfr[ci] = *(const frag8*)&Wopt[                                      \
                (((size_t)((kt_) * 4 + ks) * 16 + (w * 2 + ci)) * 64 + lane) * 8]; \
        frag8 afr[4];                                                            \
        _Pragma("unroll")                                                        \
        for (int rt = 0; rt < 4; ++rt)                                           \
            afr[rt] = *(const frag8*)&a_lds[buf_][(rt * 16 + l15) * 128 +        \
                                                  (((ks * 4 + q) ^ l15) * 8)];   \
        _Pragma("unroll")                                                        \
        for (int rt = 0; rt < 4; ++rt)                                           \
            _Pragma("unroll")                                                    \
            for (int ci = 0; ci < 2; ++ci)                                       \
                acc[rt][ci] = __builtin_amdgcn_mfma_f32_16x16x32_bf16(           \
                    afr[rt], bfr[ci], acc[rt][ci], 0, 0, 0);                     \
    } } while (0)

    // prologue: A(0) -> lds0; A(1), A(2) in flight
    LOADA(pa0, pa1, pa2, pa3, 0);
    LOADA(pb0, pb1, pb2, pb3, 1);
    CVTST(0, pa0, pa1, pa2, pa3);
    LOADA(pa0, pa1, pa2, pa3, 2);       // 2-step lead
    __syncthreads();

    STEP(0, 0);
    CVTST(1, pb0, pb1, pb2, pb3);       // A(1) landed ~2 steps ago
    LOADA(pb0, pb1, pb2, pb3, 3);       // 2-step lead
    __syncthreads();

    STEP(1, 1);
    CVTST(0, pa0, pa1, pa2, pa3);       // A(2)
    __syncthreads();

    STEP(2, 0);
    CVTST(1, pb0, pb1, pb2, pb3);       // A(3)
    __syncthreads();

    STEP(3, 1);

#undef LOADA
#undef CVTST
#undef STEP

    // epilogue: e_row = sum_col We[col] * sigmoid(h + bu[col]); wave covers 32 cols
    #pragma unroll
    for (int rt = 0; rt < 4; ++rt) {
        #pragma unroll
        for (int r = 0; r < 4; ++r) {
            float s = 0.0f;
            #pragma unroll
            for (int ci = 0; ci < 2; ++ci) {
                float h = acc[rt][ci][r] + buv[ci];
                s += wev[ci] * __builtin_amdgcn_rcpf(1.0f + __expf(-h));
            }
            s += __shfl_xor(s, 1, 64);
            s += __shfl_xor(s, 2, 64);
            s += __shfl_xor(s, 4, 64);
            s += __shfl_xor(s, 8, 64);
            if (l15 == 0) e_part[w * 64 + rt * 16 + q * 4 + r] = s;
        }
    }
    __syncthreads();
    if (tid < 64)
        e_out[m0 + tid] = e_part[tid] + e_part[64 + tid] + e_part[128 + tid] + e_part[192 + tid]
                        + e_part[256 + tid] + e_part[320 + tid] + e_part[384 + tid] + e_part[448 + tid];
}

// ---------------- kernel 3: per-segment softmax stats — MULTI-CHUNK segments only ----------------
__global__ __launch_bounds__(256) void seg_stats(
        float* __restrict__ e, const int* __restrict__ off, int B) {
    int seg = blockIdx.x * 4 + (threadIdx.x >> 6);
    int lane = threadIdx.x & 63;
    if (seg >= B) return;
    int start = off[seg];
    int len = off[seg + 1] - start;
    if (len <= CHUNK) return;          // handled in pool_chunks
    float m = -3.0e38f;
    for (int i = lane; i < len; i += 64) m = fmaxf(m, e[start + i]);
    #pragma unroll
    for (int o = 32; o > 0; o >>= 1) m = fmaxf(m, __shfl_xor(m, o, 64));
    float s = 0.0f;
    for (int i = lane; i < len; i += 64) s += __expf(e[start + i] - m);
    #pragma unroll
    for (int o = 32; o > 0; o >>= 1) s += __shfl_xor(s, o, 64);
    float inv = (s > 0.0f) ? 1.0f / s : 0.0f;
    for (int i = lane; i < len; i += 64) e[start + i] = __expf(e[start + i] - m) * inv;
}

// ---------------- kernel 4: chunked weighted pooling with fused local softmax ----------------
__global__ __launch_bounds__(256) void pool_chunks(
        const float* __restrict__ ealpha, const float* __restrict__ feats,
        const int* __restrict__ off, const int2* __restrict__ chunks,
        const int* __restrict__ chunk_cnt, float* __restrict__ rst) {
    __shared__ float redf[4 * 256];
    __shared__ float smred[8];
    int idx = blockIdx.x;
    if (idx >= chunk_cnt[0]) return;
    int2 en = chunks[idx];
    int seg = en.x, cstart = en.y;
    int sstart = off[seg], send = off[seg + 1];
    int clen = send - cstart;
    if (clen > CHUNK) clen = CHUNK;
    int tid = threadIdx.x, lane = tid & 63, g = tid >> 6;
    const bool multi = (send - sstart) > CHUNK;   // block-uniform

    float m = 0.0f, inv = 1.0f;
    if (!multi) {
        float v = (tid < clen) ? ealpha[cstart + tid] : -3.0e38f;
        #pragma unroll
        for (int o = 32; o > 0; o >>= 1) v = fmaxf(v, __shfl_xor(v, o, 64));
        if (lane == 0) smred[g] = v;
        __syncthreads();
        m = fmaxf(fmaxf(smred[0], smred[1]), fmaxf(smred[2], smred[3]));
        float x = (tid < clen) ? __expf(ealpha[cstart + tid] - m) : 0.0f;
        #pragma unroll
        for (int o = 32; o > 0; o >>= 1) x += __shfl_xor(x, o, 64);
        if (lane == 0) smred[4 + g] = x;
        __syncthreads();
        float ssum = smred[4] + smred[5] + smred[6] + smred[7];
        inv = (ssum > 0.0f) ? 1.0f / ssum : 0.0f;
    }

    const f32x4* F = (const f32x4*)feats + (size_t)cstart * 64 + lane;
    const float* A = ealpha + cstart;
    f32x4 acc0 = (f32x4)(0.0f), acc1 = (f32x4)(0.0f);
    int i = g;
    for (; i + 4 < clen; i += 8) {
        float w0 = A[i], w1 = A[i + 4];
        if (!multi) { w0 = __expf(w0 - m) * inv; w1 = __expf(w1 - m) * inv; }
        acc0 += w0 * F[(size_t)i * 64];
        acc1 += w1 * F[(size_t)(i + 4) * 64];
    }
    if (i < clen) {
        float w0 = A[i];
        if (!multi) w0 = __expf(w0 - m) * inv;
        acc0 += w0 * F[(size_t)i * 64];
    }
    acc0 += acc1;
    *(f32x4*)&redf[g * 256 + lane * 4] = acc0;
    __syncthreads();
    float v = redf[tid] + redf[256 + tid] + redf[512 + tid] + redf[768 + tid];
    if (multi) atomicAdd(&rst[(size_t)seg * H + tid], v);
    else rst[(size_t)seg * H + tid] = v;
}

// ---------------- kernel 5: out = rst @ Wout.T (via WoutT) ----------------
#define RB 8
__global__ __launch_bounds__(256) void out_gemm(
        const float* __restrict__ rst, const float* __restrict__ WoutT,
        float* __restrict__ out) {
    __shared__ float r[RB * 256];
    const int tid = threadIdx.x;
    const size_t b0 = (size_t)blockIdx.x * RB;
    for (int i = tid; i < RB * 256; i += 256) r[i] = rst[b0 * 256 + i];
    __syncthreads();
    float acc[RB];
    #pragma unroll
    for (int j = 0; j < RB; j++) acc[j] = 0.0f;
    for (int k = 0; k < 256; k += 4) {
        f32x4 rw[RB];
        #pragma unroll
        for (int j = 0; j < RB; j++) rw[j] = *(const f32x4*)&r[j * 256 + k];
        #pragma unroll
        for (int kk = 0; kk < 4; kk++) {
            float wv = WoutT[(size_t)(k + kk) * 256 + tid];
            #pragma unroll
            for (int j = 0; j < RB; j++) acc[j] += rw[j][kk] * wv;
        }
    }
    #pragma unroll
    for (int j = 0; j < RB; j++) out[(b0 + j) * 256 + tid] = acc[j];
}

// ---------------- launch ----------------
extern "C" void kernel_launch(void* const* d_in, const int* in_sizes, int n_in,
                              void* d_out, int out_size, void* d_ws, size_t ws_size,
                              hipStream_t stream) {
    const float* feats = (const float*)d_in[0];
    const float* ctx   = (const float*)d_in[1];
    const int*   lens  = (const int*)d_in[2];
    const float* Wu    = (const float*)d_in[3];
    const float* bu    = (const float*)d_in[4];
    const float* Wv    = (const float*)d_in[5];
    const float* We    = (const float*)d_in[6];
    const float* Wout  = (const float*)d_in[7];
    float* out = (float*)d_out;

    const int N = in_sizes[0] / H;    // 204800
    const int B = in_sizes[2];        // 4096
    const int maxChunks = B + (N + CHUNK - 1) / CHUNK;

    char* w = (char*)d_ws;
    auto carve = [&](size_t bytes) {
        char* p = w;
        w += (bytes + 255) & ~(size_t)255;
        return p;
    };
    int*            off    = (int*)           carve((size_t)(B + 1) * sizeof(int));
    float*          e      = (float*)         carve((size_t)N * sizeof(float));
    float*          rst    = (float*)         carve((size_t)B * H * sizeof(float));
    unsigned short* Wopt   = (unsigned short*)carve((size_t)16 * 16 * 64 * 8 * sizeof(unsigned short));
    float*          WoutT  = (float*)         carve((size_t)H * H * sizeof(float));
    int2*           chunks = (int2*)          carve((size_t)maxChunks * sizeof(int2));
    int*            ccnt   = (int*)           carve(sizeof(int));

    hipMemsetAsync(rst, 0, (size_t)B * H * sizeof(float), stream);  // for atomic combine

    prep_scan   <<<321,         256, 0, stream>>>(Wu, Wv, Wout, Wopt, WoutT,
                                                  lens, B, off, chunks, ccnt);
    fused_e     <<<N / 64,      512, 0, stream>>>(feats, ctx, Wopt, bu, We, e);
    seg_stats   <<<(B + 3) / 4, 256, 0, stream>>>(e, off, B);
    pool_chunks <<<maxChunks,   256, 0, stream>>>(e, feats, off, chunks, ccnt, rst);
    out_gemm    <<<B / RB,      256, 0, stream>>>(rst, WoutT, out);
}